// Round 4
// baseline (3745.181 us; speedup 1.0000x reference)
//
#include <hip/hip_runtime.h>

typedef __bf16 bf16_t;
typedef __bf16 bf16x8 __attribute__((ext_vector_type(8)));
typedef __bf16 bf16x4 __attribute__((ext_vector_type(4)));
typedef float f32x4 __attribute__((ext_vector_type(4)));

#define NB 16
#define NS 512
#define ND 768
#define NH 12
#define NFF 3072
#define NL 6
#define NHD 64
#define NM (NB*NS)   // 8192 token rows
static const size_t NQKV = (size_t)NB * NH * NS * NHD;   // 6,291,456 elems per Q/K/V buffer

static __device__ __forceinline__ f32x4 mfma16(bf16x8 a, bf16x8 b, f32x4 c) {
    return __builtin_amdgcn_mfma_f32_16x16x32_bf16(a, b, c, 0, 0, 0);
}

// dtype-dual load: isbf ? bf16[i] : f32[i]
static __device__ __forceinline__ float loadf(const void* p, size_t i, int isbf) {
    return isbf ? (float)((const bf16_t*)p)[i] : ((const float*)p)[i];
}

// async global->LDS, 16B per lane; LDS dest = wave-uniform base + lane*16
static __device__ __forceinline__ void gload_lds16(const bf16_t* g, bf16_t* l) {
    __builtin_amdgcn_global_load_lds((const __attribute__((address_space(1))) void*)g,
                                     (__attribute__((address_space(3))) void*)l, 16, 0, 0);
}

// -------------------- dtype detection (emb_ln_s is all-ones) --------------------
__global__ void detect_dtype(const void* elns, int* flag) {
    if (threadIdx.x == 0 && blockIdx.x == 0) {
        unsigned u = *(const unsigned*)elns;
        *flag = (u != 0x3F800000u) ? 1 : 0;
    }
}

// -------------------- weight transpose: src [K,N] (f32/bf16) -> dst bf16 [N,K] ------
__global__ __launch_bounds__(256) void transpose_bt(const void* __restrict__ src, size_t src_off,
                                                    size_t src_lstride,
                                                    bf16_t* __restrict__ dst, size_t dst_lstride,
                                                    int K, int N, const int* __restrict__ flagp) {
    const int isbf = flagp[0];
    __shared__ bf16_t t[32][33];
    int l = blockIdx.z;
    size_t so = src_off + (size_t)l * src_lstride;
    bf16_t* d = dst + (size_t)l * dst_lstride;
    int nn0 = blockIdx.x * 32, kk0 = blockIdx.y * 32;
    int tx = threadIdx.x, ty = threadIdx.y;  // 32 x 8
    #pragma unroll
    for (int i = 0; i < 4; i++)
        t[ty + i*8][tx] = (bf16_t)loadf(src, so + (size_t)(kk0 + ty + i*8) * N + nn0 + tx, isbf);
    __syncthreads();
    #pragma unroll
    for (int i = 0; i < 4; i++)
        d[(size_t)(nn0 + ty + i*8) * K + kk0 + tx] = t[tx][ty + i*8];
}

// -------------------- block reduce (sum,sumsq) over 256 threads --------------------
static __device__ __forceinline__ void blockReduce2(float& a, float& b, float* redbuf, int tid) {
    #pragma unroll
    for (int o = 32; o; o >>= 1) { a += __shfl_xor(a, o); b += __shfl_xor(b, o); }
    int wv = tid >> 6;
    if ((tid & 63) == 0) { redbuf[wv] = a; redbuf[4 + wv] = b; }
    __syncthreads();
    a = redbuf[0] + redbuf[1] + redbuf[2] + redbuf[3];
    b = redbuf[4] + redbuf[5] + redbuf[6] + redbuf[7];
    __syncthreads();
}

// -------------------- embedding segment-sum merge + pos emb + LN --------------------
__global__ __launch_bounds__(256) void embed_ln(const int* __restrict__ ids,
                                                const int* __restrict__ segs,
                                                const void* __restrict__ emb,
                                                const void* __restrict__ pos,
                                                const void* __restrict__ gamma,
                                                const void* __restrict__ beta,
                                                float* __restrict__ x, bf16_t* __restrict__ xb,
                                                const int* __restrict__ flagp) {
    const int isbf = flagp[0];
    int b = blockIdx.y, sq = blockIdx.x, tid = threadIdx.x;
    __shared__ int slo, shi;
    __shared__ float redbuf[8];
    if (tid == 0) { slo = 1 << 30; shi = -1; }
    __syncthreads();
    const int* segrow = segs + b * NS;
    const int* idrow  = ids  + b * NS;
    for (int p = tid; p < NS; p += 256)
        if (segrow[p] == sq) { atomicMin(&slo, p); atomicMax(&shi, p); }
    __syncthreads();
    int lo = slo, hi = shi;
    float vals[3];
    #pragma unroll
    for (int i = 0; i < 3; i++) {
        int d = tid + i * 256;
        float s;
        if (hi >= lo) {
            s = 0.f;
            for (int p = lo; p <= hi; p++) s += loadf(emb, (size_t)idrow[p] * ND + d, isbf);
        } else {
            s = loadf(emb, d, isbf);
        }
        vals[i] = s + loadf(pos, (size_t)sq * ND + d, isbf);
    }
    float sum = vals[0] + vals[1] + vals[2];
    float sq2 = vals[0]*vals[0] + vals[1]*vals[1] + vals[2]*vals[2];
    blockReduce2(sum, sq2, redbuf, tid);
    float mean = sum / ND;
    float var  = sq2 / ND - mean * mean;
    float rs = rsqrtf(fmaxf(var, 0.f) + 1e-12f);
    size_t rowoff = ((size_t)b * NS + sq) * ND;
    #pragma unroll
    for (int i = 0; i < 3; i++) {
        int d = tid + i * 256;
        float o = (vals[i] - mean) * rs * loadf(gamma, d, isbf) + loadf(beta, d, isbf);
        x[rowoff + d] = o;
        xb[rowoff + d] = (bf16_t)o;
    }
}

// -------------------- row LayerNorm in-place on f32 x, also emits bf16 xb ----------
__global__ __launch_bounds__(256) void ln_rows(float* __restrict__ x,
                                               const void* __restrict__ gamma, size_t goff,
                                               const void* __restrict__ beta, size_t boff,
                                               bf16_t* __restrict__ xb,
                                               const int* __restrict__ flagp) {
    const int isbf = flagp[0];
    int row = blockIdx.x, tid = threadIdx.x;
    __shared__ float redbuf[8];
    size_t rowoff = (size_t)row * ND;
    float vals[3];
    #pragma unroll
    for (int i = 0; i < 3; i++) vals[i] = x[rowoff + tid + i * 256];
    float sum = vals[0] + vals[1] + vals[2];
    float sq2 = vals[0]*vals[0] + vals[1]*vals[1] + vals[2]*vals[2];
    blockReduce2(sum, sq2, redbuf, tid);
    float mean = sum / ND;
    float var  = sq2 / ND - mean * mean;
    float rs = rsqrtf(fmaxf(var, 0.f) + 1e-12f);
    #pragma unroll
    for (int i = 0; i < 3; i++) {
        int d = tid + i * 256;
        float o = (vals[i] - mean) * rs * loadf(gamma, goff + d, isbf) + loadf(beta, boff + d, isbf);
        x[rowoff + d] = o;
        xb[rowoff + d] = (bf16_t)o;
    }
}

// -------------------- MFMA GEMM 256x256 tile: C[M,N] = A[M,K] * Bt[N,K]^T + bias ----
// 512 threads = 8 waves (2M x 4N), per-wave 128x64 output (acc[8][4] 16x16 frags).
// 2-phase double-buffered: LDS dbuf 2 x ([256][64] A + [256][64] B) = 128 KB,
// 16B-chunk XOR swizzle (chunk_stored = chunk ^ (row&7)), global_load_lds dwordx4.
// Halves L2/L3 fill traffic vs 128x128 tiles (A read N/256 x, B read M/256 x).
// mode 0: fused QKV scatter -> q/k [B,H,S,HD] bf16, v TRANSPOSED [B,H,HD,S] bf16
//         (N_=2304, bias0/1/2)
// mode 1: f32 out[idx] += C + bias0      (in-place residual accumulate)
// mode 2: bf16 out = gelu(C + bias0)     (FF1)
__global__ __launch_bounds__(512, 2) void gemm_bt(const bf16_t* __restrict__ A,
                                                  const bf16_t* __restrict__ Bt,
                                                  const void* __restrict__ bias0,
                                                  const void* __restrict__ bias1,
                                                  const void* __restrict__ bias2,
                                                  size_t boff, void* __restrict__ out,
                                                  int N_, int K_, int mode,
                                                  const int* __restrict__ flagp) {
    const int isbf = flagp[0];
    __shared__ __align__(16) bf16_t As[2][256 * 64];
    __shared__ __align__(16) bf16_t Bs[2][256 * 64];
    int tid = threadIdx.x, wave = tid >> 6, lane = tid & 63;
    int lm = lane & 15, quad = lane >> 4;
    int m0 = blockIdx.y * 256, n0 = blockIdx.x * 256;
    int wm = (wave >> 2) * 128, wn = (wave & 3) * 64;
    f32x4 acc[8][4] = {};
    const bf16_t* Ag = A + (size_t)m0 * K_;
    const bf16_t* Bg = Bt + (size_t)n0 * K_;
    int lr = lane >> 3, lc = lane & 7;
    const int nt = K_ >> 6;

    auto stage = [&](int buf, int k0) {
        #pragma unroll
        for (int j = 0; j < 4; j++) {
            int sg = wave * 4 + j;            // 32 segments of 8 rows
            int r  = sg * 8 + lr;
            int c  = lc ^ (r & 7);            // fetch the chunk that belongs at slot lc
            gload_lds16(Ag + (size_t)r * K_ + k0 + c * 8, &As[buf][sg * 512]);
            gload_lds16(Bg + (size_t)r * K_ + k0 + c * 8, &Bs[buf][sg * 512]);
        }
    };

    // prologue: stage tile 0, drain, barrier
    stage(0, 0);
    asm volatile("s_waitcnt vmcnt(0)" ::: "memory");
    __builtin_amdgcn_s_barrier();

    int cur = 0;
    for (int t = 0; t < nt; ++t) {
        if (t + 1 < nt) stage(cur ^ 1, (t + 1) << 6);   // issue next tile's DMA first
        const bf16_t* Asb = &As[cur][0];
        const bf16_t* Bsb = &Bs[cur][0];
        __builtin_amdgcn_s_setprio(1);
        #pragma unroll
        for (int ks = 0; ks < 2; ks++) {
            bf16x8 af[8], bfv[4];
            #pragma unroll
            for (int tt = 0; tt < 8; tt++) {
                int ra = wm + tt*16 + lm;
                af[tt]  = *(const bf16x8*)(Asb + ra*64 + (((ks*4 + quad) ^ (ra & 7)) << 3));
            }
            #pragma unroll
            for (int tt = 0; tt < 4; tt++) {
                int rb = wn + tt*16 + lm;
                bfv[tt] = *(const bf16x8*)(Bsb + rb*64 + (((ks*4 + quad) ^ (rb & 7)) << 3));
            }
            #pragma unroll
            for (int mt = 0; mt < 8; mt++)
                #pragma unroll
                for (int ntt = 0; ntt < 4; ntt++)
                    acc[mt][ntt] = mfma16(af[mt], bfv[ntt], acc[mt][ntt]);
        }
        __builtin_amdgcn_s_setprio(0);
        // my DMAs for the next tile must have landed before anyone reads that buffer
        asm volatile("s_waitcnt vmcnt(0)" ::: "memory");
        __builtin_amdgcn_s_barrier();
        cur ^= 1;
    }

    if (mode == 0) {
        // fused QKV scatter; V goes out transposed [B,H,HD,S]
        #pragma unroll
        for (int mt = 0; mt < 8; mt++) {
            int mrow0 = m0 + wm + mt*16 + quad*4;      // 4 consecutive rows sp0..sp0+3
            int bbx = mrow0 >> 9, sp = mrow0 & 511;
            #pragma unroll
            for (int nt2 = 0; nt2 < 4; nt2++) {
                int ncol = n0 + wn + nt2*16 + lm;
                int which = ncol / 768;
                int col = ncol - which * 768;
                const void* bsel = which == 0 ? bias0 : (which == 1 ? bias1 : bias2);
                float bs = loadf(bsel, boff + col, isbf);
                int hh = col >> 6, hd = col & 63;
                if (which == 2) {
                    bf16x4 pk;
                    #pragma unroll
                    for (int r = 0; r < 4; r++) pk[r] = (bf16_t)(acc[mt][nt2][r] + bs);
                    bf16_t* vout = (bf16_t*)out + 2 * NQKV +
                                   (((size_t)(bbx*NH + hh)) * NHD + hd) * NS + sp;
                    *(bf16x4*)vout = pk;
                } else {
                    #pragma unroll
                    for (int r = 0; r < 4; r++)
                        ((bf16_t*)out)[(size_t)which * NQKV +
                                       (((size_t)(bbx*NH + hh) * NS) + sp + r) * NHD + hd] =
                            (bf16_t)(acc[mt][nt2][r] + bs);
                }
            }
        }
    } else {
        #pragma unroll
        for (int mt = 0; mt < 8; mt++)
        #pragma unroll
        for (int nt2 = 0; nt2 < 4; nt2++)
        #pragma unroll
        for (int r = 0; r < 4; r++) {
            int mrow = m0 + wm + mt*16 + quad*4 + r;
            int ncol = n0 + wn + nt2*16 + lm;
            float val = acc[mt][nt2][r] + loadf(bias0, boff + ncol, isbf);
            size_t idx = (size_t)mrow * N_ + ncol;
            if (mode == 1) {
                ((float*)out)[idx] += val;
            } else {
                float g = 0.5f * val * (1.0f + erff(val * 0.70710678118654752f));
                ((bf16_t*)out)[idx] = (bf16_t)g;
            }
        }
    }
}

// -------------------- fused attention: per (b,h,32 q rows) --------------
// K and V^T are L2-resident (64KB each per (b,h), reused by 16 q-blocks) ->
// load MFMA fragments DIRECT from global, no LDS staging, 3 barriers total.
__global__ __launch_bounds__(256) void attn(const bf16_t* __restrict__ q,
                                            const bf16_t* __restrict__ k,
                                            const bf16_t* __restrict__ vt,
                                            const int* __restrict__ mask,
                                            bf16_t* __restrict__ ctx) {
    __shared__ __align__(16) bf16_t sc[32][520];
    __shared__ float rinv[32];
    int tid = threadIdx.x, w = tid >> 6, lane = tid & 63;
    int lm = lane & 15, quad = lane >> 4;
    int mtw = w >> 1, nhw = w & 1;
    int b = blockIdx.z, h = blockIdx.y, q0 = blockIdx.x * 32;
    const bf16_t* Qg = q + (((size_t)(b*NH + h) * NS) + q0) * NHD;
    const bf16_t* Kg = k + ((size_t)(b*NH + h) * NS) * NHD;
    const bf16_t* Vt = vt + ((size_t)(b*NH + h) * NHD) * NS;   // [HD][S]
    bf16x8 aq0 = *(const bf16x8*)(Qg + (mtw*16 + lm) * NHD + quad*8);
    bf16x8 aq1 = *(const bf16x8*)(Qg + (mtw*16 + lm) * NHD + 32 + quad*8);
    // phase A: scores = Q K^T / 8 + mask bias (K fragments direct from L2)
    #pragma unroll 2
    for (int kc = 0; kc < NS; kc += 64) {
        #pragma unroll
        for (int nt = 0; nt < 2; nt++) {
            int ncl = nhw*32 + nt*16 + lm;
            int col = kc + ncl;
            bf16x8 b0 = *(const bf16x8*)(Kg + (size_t)col * NHD + quad*8);
            bf16x8 b1 = *(const bf16x8*)(Kg + (size_t)col * NHD + 32 + quad*8);
            f32x4 a = {};
            a = mfma16(aq0, b0, a);
            a = mfma16(aq1, b1, a);
            float mb = (mask[b*NS + col] == 0) ? -1e9f : 0.0f;
            #pragma unroll
            for (int r = 0; r < 4; r++)
                sc[mtw*16 + quad*4 + r][col] = (bf16_t)(a[r] * 0.125f + mb);
        }
    }
    __syncthreads();
    // phase B: softmax, all 32 rows in parallel (row = tid/8, 8 lanes per row)
    {
        int row = tid >> 3, part = tid & 7;
        bf16_t* base = &sc[row][part * 64];
        bf16x8 pv[8];
        float mx = -3.0e38f;
        #pragma unroll
        for (int i = 0; i < 8; i++) {
            pv[i] = *(const bf16x8*)(base + i * 8);
            #pragma unroll
            for (int j = 0; j < 8; j++) mx = fmaxf(mx, (float)pv[i][j]);
        }
        mx = fmaxf(mx, __shfl_xor(mx, 1));
        mx = fmaxf(mx, __shfl_xor(mx, 2));
        mx = fmaxf(mx, __shfl_xor(mx, 4));
        float sum = 0.f;
        #pragma unroll
        for (int i = 0; i < 8; i++) {
            bf16x8 pe;
            #pragma unroll
            for (int j = 0; j < 8; j++) {
                float p = __expf((float)pv[i][j] - mx);
                pe[j] = (bf16_t)p;
                sum += p;
            }
            *(bf16x8*)(base + i * 8) = pe;
        }
        sum += __shfl_xor(sum, 1);
        sum += __shfl_xor(sum, 2);
        sum += __shfl_xor(sum, 4);
        if (part == 0) rinv[row] = 1.0f / sum;
    }
    __syncthreads();
    // phase C: ctx = P V (V^T fragments direct from L2), scale by 1/sum at the end
    f32x4 oc[2] = {};
    #pragma unroll 2
    for (int kc = 0; kc < NS; kc += 64) {
        #pragma unroll
        for (int ks = 0; ks < 2; ks++) {
            bf16x8 ap = *(const bf16x8*)(&sc[mtw*16 + lm][kc + ks*32 + quad*8]);
            #pragma unroll
            for (int nt = 0; nt < 2; nt++) {
                int d = nhw*32 + nt*16 + lm;
                bf16x8 bv = *(const bf16x8*)(Vt + (size_t)d * NS + kc + ks*32 + quad*8);
                oc[nt] = mfma16(ap, bv, oc[nt]);
            }
        }
    }
    #pragma unroll
    for (int nt = 0; nt < 2; nt++)
    #pragma unroll
    for (int r = 0; r < 4; r++) {
        int row = mtw*16 + quad*4 + r;
        float val = oc[nt][r] * rinv[row];
        ctx[((size_t)(b*NS) + q0 + row) * ND + h*NHD + nhw*32 + nt*16 + lm] = (bf16_t)val;
    }
}

// -------------------- classifier head, stage 1: pr[b,n] = relu(x[b,0,:] @ preW + preb)
__global__ __launch_bounds__(256) void head_pre(const float* __restrict__ x,
                                                const void* __restrict__ preW,
                                                const void* __restrict__ preb,
                                                float* __restrict__ pr,
                                                const int* __restrict__ flagp) {
    const int isbf = flagp[0];
    int b = blockIdx.y;
    int n = blockIdx.x * 256 + threadIdx.x;
    const float* xr = x + (size_t)b * NS * ND;
    float s = loadf(preb, n, isbf);
    #pragma unroll 4
    for (int kk = 0; kk < ND; kk++) s += xr[kk] * loadf(preW, (size_t)kk * ND + n, isbf);
    pr[b * ND + n] = fmaxf(s, 0.f);
}

// -------------------- classifier head, stage 2: logits = pr @ clsW + clsb ----------
__global__ __launch_bounds__(256) void head_cls(const float* __restrict__ pr,
                                                const void* __restrict__ clsW,
                                                const void* __restrict__ clsb,
                                                void* __restrict__ out,
                                                const int* __restrict__ flagp) {
    const int isbf = flagp[0];
    int b = blockIdx.x, tid = threadIdx.x;
    __shared__ float red[256];
    for (int c = 0; c < 3; c++) {
        float s = 0.f;
        for (int kk = tid; kk < ND; kk += 256) s += pr[b * ND + kk] * loadf(clsW, kk * 3 + c, isbf);
        red[tid] = s;
        __syncthreads();
        for (int off = 128; off; off >>= 1) {
            if (tid < off) red[tid] += red[tid + off];
            __syncthreads();
        }
        if (tid == 0) {
            float v = red[0] + loadf(clsb, c, isbf);
            if (isbf) ((bf16_t*)out)[b * 3 + c] = (bf16_t)v;
            else      ((float*)out)[b * 3 + c] = v;
        }
        __syncthreads();
    }
}

extern "C" void kernel_launch(void* const* d_in, const int* in_sizes, int n_in,
                              void* d_out, int out_size, void* d_ws, size_t ws_size,
                              hipStream_t stream) {
    const int* ids   = (const int*)d_in[0];
    const int* segs  = (const int*)d_in[1];
    const int* mask  = (const int*)d_in[2];
    const void* emb  = d_in[4];
    const void* pos  = d_in[5];
    const void* elns = d_in[6];
    const void* elnb = d_in[7];
    const void* Wq = d_in[8];  const void* bq = d_in[9];
    const void* Wk = d_in[10]; const void* bk = d_in[11];
    const void* Wv = d_in[12]; const void* bv = d_in[13];
    const void* Wo = d_in[14]; const void* bo = d_in[15];
    const void* l1s = d_in[16]; const void* l1b = d_in[17];
    const void* W1 = d_in[18];  const void* b1 = d_in[19];
    const void* W2 = d_in[20];  const void* b2 = d_in[21];
    const void* l2s = d_in[22]; const void* l2b = d_in[23];
    const void* preW = d_in[24]; const void* preb = d_in[25];
    const void* clsW = d_in[26]; const void* clsb = d_in[27];

    // ---- workspace layout (deterministic function of ws_size) ----
    const size_t SZ_QKVB = NQKV * 2;                 // one of q/k/v/ctx, bf16
    size_t off = 0;
    auto alloc = [&](size_t sz) { size_t o = off; off = (off + sz + 255) & ~(size_t)255; return o; };
    size_t o_qkv  = alloc(3 * SZ_QKVB);              // q|k|v, also start of h1b alias
    size_t o_ctx  = alloc(SZ_QKVB);                  // h1b = [o_qkv .. o_ctx+SZ_QKVB) = 50.3MB
    size_t o_x    = alloc((size_t)NM * ND * 4);
    size_t o_xb   = alloc((size_t)NM * ND * 2);
    size_t o_pr   = alloc((size_t)NB * ND * 4);
    size_t o_flag = alloc(256);
    size_t o_w    = off;
    const size_t WQKV_L = (size_t)3 * ND * ND;       // per-layer fused qkv weight elems
    const size_t WSQ = (size_t)ND * ND, WF = (size_t)ND * NFF;
    size_t need_big = o_w + (NL * (WQKV_L + WSQ + 2 * WF)) * 2;
    int big = ws_size >= need_big;

    char* ws = (char*)d_ws;
    bf16_t* qkv  = (bf16_t*)(ws + o_qkv);
    bf16_t* ctxb = (bf16_t*)(ws + o_ctx);
    bf16_t* h1b  = (bf16_t*)(ws + o_qkv);
    float*  x    = (float*)(ws + o_x);
    bf16_t* xb   = (bf16_t*)(ws + o_xb);
    float*  pr   = (float*)(ws + o_pr);
    int*    flag = (int*)(ws + o_flag);
    size_t nlw = big ? NL : 1;
    bf16_t* wqkv = (bf16_t*)(ws + o_w);
    bf16_t* wo_t = wqkv + nlw * WQKV_L;
    bf16_t* w1_t = wo_t + nlw * WSQ;
    bf16_t* w2_t = w1_t + nlw * WF;

    detect_dtype<<<1, 64, 0, stream>>>(elns, flag);
    embed_ln<<<dim3(NS, NB), 256, 0, stream>>>(ids, segs, emb, pos, elns, elnb, x, xb, flag);

    dim3 tb(32, 8);
    if (big) {
        transpose_bt<<<dim3(24, 24, NL), tb, 0, stream>>>(Wq, 0, WSQ, wqkv,            WQKV_L, ND, ND, flag);
        transpose_bt<<<dim3(24, 24, NL), tb, 0, stream>>>(Wk, 0, WSQ, wqkv + WSQ,      WQKV_L, ND, ND, flag);
        transpose_bt<<<dim3(24, 24, NL), tb, 0, stream>>>(Wv, 0, WSQ, wqkv + 2 * WSQ,  WQKV_L, ND, ND, flag);
        transpose_bt<<<dim3(24, 24, NL), tb, 0, stream>>>(Wo, 0, WSQ, wo_t, WSQ, ND, ND, flag);
        transpose_bt<<<dim3(96, 24, NL), tb, 0, stream>>>(W1, 0, WF, w1_t, WF, ND, NFF, flag);
        transpose_bt<<<dim3(24, 96, NL), tb, 0, stream>>>(W2, 0, WF, w2_t, WF, NFF, ND, flag);
    }

    for (int l = 0; l < NL; l++) {
        if (!big) {
            transpose_bt<<<dim3(24, 24, 1), tb, 0, stream>>>(Wq, (size_t)l * WSQ, 0, wqkv,           0, ND, ND, flag);
            transpose_bt<<<dim3(24, 24, 1), tb, 0, stream>>>(Wk, (size_t)l * WSQ, 0, wqkv + WSQ,     0, ND, ND, flag);
            transpose_bt<<<dim3(24, 24, 1), tb, 0, stream>>>(Wv, (size_t)l * WSQ, 0, wqkv + 2 * WSQ, 0, ND, ND, flag);
            transpose_bt<<<dim3(24, 24, 1), tb, 0, stream>>>(Wo, (size_t)l * WSQ, 0, wo_t, 0, ND, ND, flag);
            transpose_bt<<<dim3(96, 24, 1), tb, 0, stream>>>(W1, (size_t)l * WF, 0, w1_t, 0, ND, NFF, flag);
            transpose_bt<<<dim3(24, 96, 1), tb, 0, stream>>>(W2, (size_t)l * WF, 0, w2_t, 0, NFF, ND, flag);
        }
        const bf16_t* wqkv_l = big ? wqkv + (size_t)l * WQKV_L : wqkv;
        const bf16_t* wo_l   = big ? wo_t + (size_t)l * WSQ : wo_t;
        const bf16_t* w1_l   = big ? w1_t + (size_t)l * WF : w1_t;
        const bf16_t* w2_l   = big ? w2_t + (size_t)l * WF : w2_t;

        gemm_bt<<<dim3(9, 32), 512, 0, stream>>>(xb, wqkv_l, bq, bk, bv, (size_t)l * ND, qkv, 2304, ND, 0, flag);
        attn<<<dim3(16, NH, NB), 256, 0, stream>>>(qkv, qkv + NQKV, qkv + 2 * NQKV, mask, ctxb);
        gemm_bt<<<dim3(3, 32), 512, 0, stream>>>(ctxb, wo_l, bo, nullptr, nullptr, (size_t)l * ND, x, ND, ND, 1, flag);
        ln_rows<<<NM, 256, 0, stream>>>(x, l1s, (size_t)l * ND, l1b, (size_t)l * ND, xb, flag);
        gemm_bt<<<dim3(12, 32), 512, 0, stream>>>(xb, w1_l, b1, nullptr, nullptr, (size_t)l * NFF, h1b, NFF, ND, 2, flag);
        gemm_bt<<<dim3(3, 32), 512, 0, stream>>>(h1b, w2_l, b2, nullptr, nullptr, (size_t)l * ND, x, ND, NFF, 1, flag);
        ln_rows<<<NM, 256, 0, stream>>>(x, l2s, (size_t)l * ND, l2b, (size_t)l * ND, xb, flag);
    }

    head_pre<<<dim3(3, NB), 256, 0, stream>>>(x, preW, preb, pr, flag);
    head_cls<<<NB, 256, 0, stream>>>(pr, clsW, clsb, d_out, flag);
}

// Round 5
// 3531.105 us; speedup vs baseline: 1.0606x; 1.0606x over previous
//
#include <hip/hip_runtime.h>

typedef __bf16 bf16_t;
typedef __bf16 bf16x8 __attribute__((ext_vector_type(8)));
typedef __bf16 bf16x4 __attribute__((ext_vector_type(4)));
typedef float f32x4 __attribute__((ext_vector_type(4)));

#define NB 16
#define NS 512
#define ND 768
#define NH 12
#define NFF 3072
#define NL 6
#define NHD 64
#define NM (NB*NS)   // 8192 token rows
static const size_t NQKV = (size_t)NB * NH * NS * NHD;   // 6,291,456 elems per Q/K/V buffer

static __device__ __forceinline__ f32x4 mfma16(bf16x8 a, bf16x8 b, f32x4 c) {
    return __builtin_amdgcn_mfma_f32_16x16x32_bf16(a, b, c, 0, 0, 0);
}

// dtype-dual load: isbf ? bf16[i] : f32[i]
static __device__ __forceinline__ float loadf(const void* p, size_t i, int isbf) {
    return isbf ? (float)((const bf16_t*)p)[i] : ((const float*)p)[i];
}

// async global->LDS, 16B per lane; LDS dest = wave-uniform base + lane*16
static __device__ __forceinline__ void gload_lds16(const bf16_t* g, bf16_t* l) {
    __builtin_amdgcn_global_load_lds((const __attribute__((address_space(1))) void*)g,
                                     (__attribute__((address_space(3))) void*)l, 16, 0, 0);
}

// -------------------- dtype detection (emb_ln_s is all-ones) --------------------
__global__ void detect_dtype(const void* elns, int* flag) {
    if (threadIdx.x == 0 && blockIdx.x == 0) {
        unsigned u = *(const unsigned*)elns;
        *flag = (u != 0x3F800000u) ? 1 : 0;
    }
}

// -------------------- weight transpose: src [K,N] (f32/bf16) -> dst bf16 [N,K] ------
__global__ __launch_bounds__(256) void transpose_bt(const void* __restrict__ src, size_t src_off,
                                                    size_t src_lstride,
                                                    bf16_t* __restrict__ dst, size_t dst_lstride,
                                                    int K, int N, const int* __restrict__ flagp) {
    const int isbf = flagp[0];
    __shared__ bf16_t t[32][33];
    int l = blockIdx.z;
    size_t so = src_off + (size_t)l * src_lstride;
    bf16_t* d = dst + (size_t)l * dst_lstride;
    int nn0 = blockIdx.x * 32, kk0 = blockIdx.y * 32;
    int tx = threadIdx.x, ty = threadIdx.y;  // 32 x 8
    #pragma unroll
    for (int i = 0; i < 4; i++)
        t[ty + i*8][tx] = (bf16_t)loadf(src, so + (size_t)(kk0 + ty + i*8) * N + nn0 + tx, isbf);
    __syncthreads();
    #pragma unroll
    for (int i = 0; i < 4; i++)
        d[(size_t)(nn0 + ty + i*8) * K + kk0 + tx] = t[tx][ty + i*8];
}

// -------------------- block reduce (sum,sumsq) over 256 threads --------------------
static __device__ __forceinline__ void blockReduce2(float& a, float& b, float* redbuf, int tid) {
    #pragma unroll
    for (int o = 32; o; o >>= 1) { a += __shfl_xor(a, o); b += __shfl_xor(b, o); }
    int wv = tid >> 6;
    if ((tid & 63) == 0) { redbuf[wv] = a; redbuf[4 + wv] = b; }
    __syncthreads();
    a = redbuf[0] + redbuf[1] + redbuf[2] + redbuf[3];
    b = redbuf[4] + redbuf[5] + redbuf[6] + redbuf[7];
    __syncthreads();
}

// -------------------- embedding segment-sum merge + pos emb + LN --------------------
__global__ __launch_bounds__(256) void embed_ln(const int* __restrict__ ids,
                                                const int* __restrict__ segs,
                                                const void* __restrict__ emb,
                                                const void* __restrict__ pos,
                                                const void* __restrict__ gamma,
                                                const void* __restrict__ beta,
                                                float* __restrict__ x, bf16_t* __restrict__ xb,
                                                const int* __restrict__ flagp) {
    const int isbf = flagp[0];
    int b = blockIdx.y, sq = blockIdx.x, tid = threadIdx.x;
    __shared__ int slo, shi;
    __shared__ float redbuf[8];
    if (tid == 0) { slo = 1 << 30; shi = -1; }
    __syncthreads();
    const int* segrow = segs + b * NS;
    const int* idrow  = ids  + b * NS;
    for (int p = tid; p < NS; p += 256)
        if (segrow[p] == sq) { atomicMin(&slo, p); atomicMax(&shi, p); }
    __syncthreads();
    int lo = slo, hi = shi;
    float vals[3];
    #pragma unroll
    for (int i = 0; i < 3; i++) {
        int d = tid + i * 256;
        float s;
        if (hi >= lo) {
            s = 0.f;
            for (int p = lo; p <= hi; p++) s += loadf(emb, (size_t)idrow[p] * ND + d, isbf);
        } else {
            s = loadf(emb, d, isbf);
        }
        vals[i] = s + loadf(pos, (size_t)sq * ND + d, isbf);
    }
    float sum = vals[0] + vals[1] + vals[2];
    float sq2 = vals[0]*vals[0] + vals[1]*vals[1] + vals[2]*vals[2];
    blockReduce2(sum, sq2, redbuf, tid);
    float mean = sum / ND;
    float var  = sq2 / ND - mean * mean;
    float rs = rsqrtf(fmaxf(var, 0.f) + 1e-12f);
    size_t rowoff = ((size_t)b * NS + sq) * ND;
    #pragma unroll
    for (int i = 0; i < 3; i++) {
        int d = tid + i * 256;
        float o = (vals[i] - mean) * rs * loadf(gamma, d, isbf) + loadf(beta, d, isbf);
        x[rowoff + d] = o;
        xb[rowoff + d] = (bf16_t)o;
    }
}

// -------------------- row LayerNorm in-place on f32 x, also emits bf16 xb ----------
__global__ __launch_bounds__(256) void ln_rows(float* __restrict__ x,
                                               const void* __restrict__ gamma, size_t goff,
                                               const void* __restrict__ beta, size_t boff,
                                               bf16_t* __restrict__ xb,
                                               const int* __restrict__ flagp) {
    const int isbf = flagp[0];
    int row = blockIdx.x, tid = threadIdx.x;
    __shared__ float redbuf[8];
    size_t rowoff = (size_t)row * ND;
    float vals[3];
    #pragma unroll
    for (int i = 0; i < 3; i++) vals[i] = x[rowoff + tid + i * 256];
    float sum = vals[0] + vals[1] + vals[2];
    float sq2 = vals[0]*vals[0] + vals[1]*vals[1] + vals[2]*vals[2];
    blockReduce2(sum, sq2, redbuf, tid);
    float mean = sum / ND;
    float var  = sq2 / ND - mean * mean;
    float rs = rsqrtf(fmaxf(var, 0.f) + 1e-12f);
    #pragma unroll
    for (int i = 0; i < 3; i++) {
        int d = tid + i * 256;
        float o = (vals[i] - mean) * rs * loadf(gamma, goff + d, isbf) + loadf(beta, boff + d, isbf);
        x[rowoff + d] = o;
        xb[rowoff + d] = (bf16_t)o;
    }
}

// -------------------- MFMA GEMM: C[M,N] = A[M,K] * Bt[N,K]^T + bias --------------------
// 128x128 tile, 4 waves. A staged in LDS double-buffer (2 x 16 KB = 32 KB ->
// up to 5 blocks/CU); B (pre-transposed weights, L2-resident: 1.2-4.7 MB reused
// 48-64x) loaded DIRECT from global into VGPR fragments - no Bs staging, no
// barrier-protected B bytes. 16B-chunk XOR swizzle on As, global_load_lds dwordx4.
// mode 0: fused QKV scatter -> q/k [B,H,S,HD] bf16, v TRANSPOSED [B,H,HD,S] bf16
//         (N_=2304, bias0/1/2)
// mode 1: f32 out[idx] += C + bias0      (in-place residual accumulate)
// mode 2: bf16 out = gelu(C + bias0)     (FF1)
__global__ __launch_bounds__(256, 4) void gemm_bt(const bf16_t* __restrict__ A,
                                                  const bf16_t* __restrict__ Bt,
                                                  const void* __restrict__ bias0,
                                                  const void* __restrict__ bias1,
                                                  const void* __restrict__ bias2,
                                                  size_t boff, void* __restrict__ out,
                                                  int N_, int K_, int mode,
                                                  const int* __restrict__ flagp) {
    const int isbf = flagp[0];
    __shared__ __align__(16) bf16_t As[2][128 * 64];   // 32 KB total
    int tid = threadIdx.x, wave = tid >> 6, lane = tid & 63;
    int lm = lane & 15, quad = lane >> 4;
    int m0 = blockIdx.y * 128, n0 = blockIdx.x * 128;
    int wm = (wave >> 1) * 64, wn = (wave & 1) * 64;
    f32x4 acc[4][4] = {};
    const bf16_t* Ag = A + (size_t)m0 * K_;
    const bf16_t* Bg = Bt + (size_t)n0 * K_;
    int lr = lane >> 3, lc = lane & 7;
    const int nt = K_ >> 6;

    auto stageA = [&](int buf, int k0) {
        #pragma unroll
        for (int j = 0; j < 4; j++) {
            int sg = wave * 4 + j;            // 16 segments of 8 rows
            int r  = sg * 8 + lr;
            int c  = lc ^ (r & 7);            // fetch the chunk that belongs at slot lc
            gload_lds16(Ag + (size_t)r * K_ + k0 + c * 8, &As[buf][sg * 512]);
        }
    };

    // prologue: stage tile 0, drain, barrier
    stageA(0, 0);
    asm volatile("s_waitcnt vmcnt(0)" ::: "memory");
    __builtin_amdgcn_s_barrier();

    int cur = 0;
    for (int t = 0; t < nt; ++t) {
        int k0 = t << 6;
        if (t + 1 < nt) stageA(cur ^ 1, k0 + 64);   // issue next A-tile's DMA first
        const bf16_t* Asb = &As[cur][0];
        __builtin_amdgcn_s_setprio(1);
        #pragma unroll
        for (int ks = 0; ks < 2; ks++) {
            // B fragments direct from global (L2-resident weight panel)
            bf16x8 bfv[4];
            #pragma unroll
            for (int tt = 0; tt < 4; tt++) {
                int rb = wn + tt*16 + lm;
                bfv[tt] = *(const bf16x8*)(Bg + (size_t)rb * K_ + k0 + ((ks*4 + quad) << 3));
            }
            bf16x8 af[4];
            #pragma unroll
            for (int tt = 0; tt < 4; tt++) {
                int ra = wm + tt*16 + lm;
                af[tt] = *(const bf16x8*)(Asb + ra*64 + (((ks*4 + quad) ^ (ra & 7)) << 3));
            }
            #pragma unroll
            for (int mt = 0; mt < 4; mt++)
                #pragma unroll
                for (int ntt = 0; ntt < 4; ntt++)
                    acc[mt][ntt] = mfma16(af[mt], bfv[ntt], acc[mt][ntt]);
        }
        __builtin_amdgcn_s_setprio(0);
        // my A-DMAs for the next tile must have landed before anyone reads that buffer
        asm volatile("s_waitcnt vmcnt(0)" ::: "memory");
        __builtin_amdgcn_s_barrier();
        cur ^= 1;
    }

    if (mode == 0) {
        // fused QKV scatter; V goes out transposed [B,H,HD,S]
        #pragma unroll
        for (int mt = 0; mt < 4; mt++) {
            int mrow0 = m0 + wm + mt*16 + quad*4;      // 4 consecutive rows sp0..sp0+3
            int bbx = mrow0 >> 9, sp = mrow0 & 511;
            #pragma unroll
            for (int nt2 = 0; nt2 < 4; nt2++) {
                int ncol = n0 + wn + nt2*16 + lm;
                int which = ncol / 768;
                int col = ncol - which * 768;
                const void* bsel = which == 0 ? bias0 : (which == 1 ? bias1 : bias2);
                float bs = loadf(bsel, boff + col, isbf);
                int hh = col >> 6, hd = col & 63;
                if (which == 2) {
                    bf16x4 pk;
                    #pragma unroll
                    for (int r = 0; r < 4; r++) pk[r] = (bf16_t)(acc[mt][nt2][r] + bs);
                    bf16_t* vout = (bf16_t*)out + 2 * NQKV +
                                   (((size_t)(bbx*NH + hh)) * NHD + hd) * NS + sp;
                    *(bf16x4*)vout = pk;
                } else {
                    #pragma unroll
                    for (int r = 0; r < 4; r++)
                        ((bf16_t*)out)[(size_t)which * NQKV +
                                       (((size_t)(bbx*NH + hh) * NS) + sp + r) * NHD + hd] =
                            (bf16_t)(acc[mt][nt2][r] + bs);
                }
            }
        }
    } else {
        #pragma unroll
        for (int mt = 0; mt < 4; mt++)
        #pragma unroll
        for (int nt2 = 0; nt2 < 4; nt2++)
        #pragma unroll
        for (int r = 0; r < 4; r++) {
            int mrow = m0 + wm + mt*16 + quad*4 + r;
            int ncol = n0 + wn + nt2*16 + lm;
            float val = acc[mt][nt2][r] + loadf(bias0, boff + ncol, isbf);
            size_t idx = (size_t)mrow * N_ + ncol;
            if (mode == 1) {
                ((float*)out)[idx] += val;
            } else {
                float g = 0.5f * val * (1.0f + erff(val * 0.70710678118654752f));
                ((bf16_t*)out)[idx] = (bf16_t)g;
            }
        }
    }
}

// -------------------- fused attention: per (b,h,32 q rows) --------------
// K and V^T are L2-resident (64KB each per (b,h), reused by 16 q-blocks) ->
// load MFMA fragments DIRECT from global, no LDS staging, 3 barriers total.
__global__ __launch_bounds__(256) void attn(const bf16_t* __restrict__ q,
                                            const bf16_t* __restrict__ k,
                                            const bf16_t* __restrict__ vt,
                                            const int* __restrict__ mask,
                                            bf16_t* __restrict__ ctx) {
    __shared__ __align__(16) bf16_t sc[32][520];
    __shared__ float rinv[32];
    int tid = threadIdx.x, w = tid >> 6, lane = tid & 63;
    int lm = lane & 15, quad = lane >> 4;
    int mtw = w >> 1, nhw = w & 1;
    int b = blockIdx.z, h = blockIdx.y, q0 = blockIdx.x * 32;
    const bf16_t* Qg = q + (((size_t)(b*NH + h) * NS) + q0) * NHD;
    const bf16_t* Kg = k + ((size_t)(b*NH + h) * NS) * NHD;
    const bf16_t* Vt = vt + ((size_t)(b*NH + h) * NHD) * NS;   // [HD][S]
    bf16x8 aq0 = *(const bf16x8*)(Qg + (mtw*16 + lm) * NHD + quad*8);
    bf16x8 aq1 = *(const bf16x8*)(Qg + (mtw*16 + lm) * NHD + 32 + quad*8);
    // phase A: scores = Q K^T / 8 + mask bias (K fragments direct from L2)
    #pragma unroll 2
    for (int kc = 0; kc < NS; kc += 64) {
        #pragma unroll
        for (int nt = 0; nt < 2; nt++) {
            int ncl = nhw*32 + nt*16 + lm;
            int col = kc + ncl;
            bf16x8 b0 = *(const bf16x8*)(Kg + (size_t)col * NHD + quad*8);
            bf16x8 b1 = *(const bf16x8*)(Kg + (size_t)col * NHD + 32 + quad*8);
            f32x4 a = {};
            a = mfma16(aq0, b0, a);
            a = mfma16(aq1, b1, a);
            float mb = (mask[b*NS + col] == 0) ? -1e9f : 0.0f;
            #pragma unroll
            for (int r = 0; r < 4; r++)
                sc[mtw*16 + quad*4 + r][col] = (bf16_t)(a[r] * 0.125f + mb);
        }
    }
    __syncthreads();
    // phase B: softmax, all 32 rows in parallel (row = tid/8, 8 lanes per row)
    {
        int row = tid >> 3, part = tid & 7;
        bf16_t* base = &sc[row][part * 64];
        bf16x8 pv[8];
        float mx = -3.0e38f;
        #pragma unroll
        for (int i = 0; i < 8; i++) {
            pv[i] = *(const bf16x8*)(base + i * 8);
            #pragma unroll
            for (int j = 0; j < 8; j++) mx = fmaxf(mx, (float)pv[i][j]);
        }
        mx = fmaxf(mx, __shfl_xor(mx, 1));
        mx = fmaxf(mx, __shfl_xor(mx, 2));
        mx = fmaxf(mx, __shfl_xor(mx, 4));
        float sum = 0.f;
        #pragma unroll
        for (int i = 0; i < 8; i++) {
            bf16x8 pe;
            #pragma unroll
            for (int j = 0; j < 8; j++) {
                float p = __expf((float)pv[i][j] - mx);
                pe[j] = (bf16_t)p;
                sum += p;
            }
            *(bf16x8*)(base + i * 8) = pe;
        }
        sum += __shfl_xor(sum, 1);
        sum += __shfl_xor(sum, 2);
        sum += __shfl_xor(sum, 4);
        if (part == 0) rinv[row] = 1.0f / sum;
    }
    __syncthreads();
    // phase C: ctx = P V (V^T fragments direct from L2), scale by 1/sum at the end
    f32x4 oc[2] = {};
    #pragma unroll 2
    for (int kc = 0; kc < NS; kc += 64) {
        #pragma unroll
        for (int ks = 0; ks < 2; ks++) {
            bf16x8 ap = *(const bf16x8*)(&sc[mtw*16 + lm][kc + ks*32 + quad*8]);
            #pragma unroll
            for (int nt = 0; nt < 2; nt++) {
                int d = nhw*32 + nt*16 + lm;
                bf16x8 bv = *(const bf16x8*)(Vt + (size_t)d * NS + kc + ks*32 + quad*8);
                oc[nt] = mfma16(ap, bv, oc[nt]);
            }
        }
    }
    #pragma unroll
    for (int nt = 0; nt < 2; nt++)
    #pragma unroll
    for (int r = 0; r < 4; r++) {
        int row = mtw*16 + quad*4 + r;
        float val = oc[nt][r] * rinv[row];
        ctx[((size_t)(b*NS) + q0 + row) * ND + h*NHD + nhw*32 + nt*16 + lm] = (bf16_t)val;
    }
}

// -------------------- classifier head, stage 1: pr[b,n] = relu(x[b,0,:] @ preW + preb)
__global__ __launch_bounds__(256) void head_pre(const float* __restrict__ x,
                                                const void* __restrict__ preW,
                                                const void* __restrict__ preb,
                                                float* __restrict__ pr,
                                                const int* __restrict__ flagp) {
    const int isbf = flagp[0];
    int b = blockIdx.y;
    int n = blockIdx.x * 256 + threadIdx.x;
    const float* xr = x + (size_t)b * NS * ND;
    float s = loadf(preb, n, isbf);
    #pragma unroll 4
    for (int kk = 0; kk < ND; kk++) s += xr[kk] * loadf(preW, (size_t)kk * ND + n, isbf);
    pr[b * ND + n] = fmaxf(s, 0.f);
}

// -------------------- classifier head, stage 2: logits = pr @ clsW + clsb ----------
__global__ __launch_bounds__(256) void head_cls(const float* __restrict__ pr,
                                                const void* __restrict__ clsW,
                                                const void* __restrict__ clsb,
                                                void* __restrict__ out,
                                                const int* __restrict__ flagp) {
    const int isbf = flagp[0];
    int b = blockIdx.x, tid = threadIdx.x;
    __shared__ float red[256];
    for (int c = 0; c < 3; c++) {
        float s = 0.f;
        for (int kk = tid; kk < ND; kk += 256) s += pr[b * ND + kk] * loadf(clsW, kk * 3 + c, isbf);
        red[tid] = s;
        __syncthreads();
        for (int off = 128; off; off >>= 1) {
            if (tid < off) red[tid] += red[tid + off];
            __syncthreads();
        }
        if (tid == 0) {
            float v = red[0] + loadf(clsb, c, isbf);
            if (isbf) ((bf16_t*)out)[b * 3 + c] = (bf16_t)v;
            else      ((float*)out)[b * 3 + c] = v;
        }
        __syncthreads();
    }
}

extern "C" void kernel_launch(void* const* d_in, const int* in_sizes, int n_in,
                              void* d_out, int out_size, void* d_ws, size_t ws_size,
                              hipStream_t stream) {
    const int* ids   = (const int*)d_in[0];
    const int* segs  = (const int*)d_in[1];
    const int* mask  = (const int*)d_in[2];
    const void* emb  = d_in[4];
    const void* pos  = d_in[5];
    const void* elns = d_in[6];
    const void* elnb = d_in[7];
    const void* Wq = d_in[8];  const void* bq = d_in[9];
    const void* Wk = d_in[10]; const void* bk = d_in[11];
    const void* Wv = d_in[12]; const void* bv = d_in[13];
    const void* Wo = d_in[14]; const void* bo = d_in[15];
    const void* l1s = d_in[16]; const void* l1b = d_in[17];
    const void* W1 = d_in[18];  const void* b1 = d_in[19];
    const void* W2 = d_in[20];  const void* b2 = d_in[21];
    const void* l2s = d_in[22]; const void* l2b = d_in[23];
    const void* preW = d_in[24]; const void* preb = d_in[25];
    const void* clsW = d_in[26]; const void* clsb = d_in[27];

    // ---- workspace layout (deterministic function of ws_size) ----
    const size_t SZ_QKVB = NQKV * 2;                 // one of q/k/v/ctx, bf16
    size_t off = 0;
    auto alloc = [&](size_t sz) { size_t o = off; off = (off + sz + 255) & ~(size_t)255; return o; };
    size_t o_qkv  = alloc(3 * SZ_QKVB);              // q|k|v, also start of h1b alias
    size_t o_ctx  = alloc(SZ_QKVB);                  // h1b = [o_qkv .. o_ctx+SZ_QKVB) = 50.3MB
    size_t o_x    = alloc((size_t)NM * ND * 4);
    size_t o_xb   = alloc((size_t)NM * ND * 2);
    size_t o_pr   = alloc((size_t)NB * ND * 4);
    size_t o_flag = alloc(256);
    size_t o_w    = off;
    const size_t WQKV_L = (size_t)3 * ND * ND;       // per-layer fused qkv weight elems
    const size_t WSQ = (size_t)ND * ND, WF = (size_t)ND * NFF;
    size_t need_big = o_w + (NL * (WQKV_L + WSQ + 2 * WF)) * 2;
    int big = ws_size >= need_big;

    char* ws = (char*)d_ws;
    bf16_t* qkv  = (bf16_t*)(ws + o_qkv);
    bf16_t* ctxb = (bf16_t*)(ws + o_ctx);
    bf16_t* h1b  = (bf16_t*)(ws + o_qkv);
    float*  x    = (float*)(ws + o_x);
    bf16_t* xb   = (bf16_t*)(ws + o_xb);
    float*  pr   = (float*)(ws + o_pr);
    int*    flag = (int*)(ws + o_flag);
    size_t nlw = big ? NL : 1;
    bf16_t* wqkv = (bf16_t*)(ws + o_w);
    bf16_t* wo_t = wqkv + nlw * WQKV_L;
    bf16_t* w1_t = wo_t + nlw * WSQ;
    bf16_t* w2_t = w1_t + nlw * WF;

    detect_dtype<<<1, 64, 0, stream>>>(elns, flag);
    embed_ln<<<dim3(NS, NB), 256, 0, stream>>>(ids, segs, emb, pos, elns, elnb, x, xb, flag);

    dim3 tb(32, 8);
    if (big) {
        transpose_bt<<<dim3(24, 24, NL), tb, 0, stream>>>(Wq, 0, WSQ, wqkv,            WQKV_L, ND, ND, flag);
        transpose_bt<<<dim3(24, 24, NL), tb, 0, stream>>>(Wk, 0, WSQ, wqkv + WSQ,      WQKV_L, ND, ND, flag);
        transpose_bt<<<dim3(24, 24, NL), tb, 0, stream>>>(Wv, 0, WSQ, wqkv + 2 * WSQ,  WQKV_L, ND, ND, flag);
        transpose_bt<<<dim3(24, 24, NL), tb, 0, stream>>>(Wo, 0, WSQ, wo_t, WSQ, ND, ND, flag);
        transpose_bt<<<dim3(96, 24, NL), tb, 0, stream>>>(W1, 0, WF, w1_t, WF, ND, NFF, flag);
        transpose_bt<<<dim3(24, 96, NL), tb, 0, stream>>>(W2, 0, WF, w2_t, WF, NFF, ND, flag);
    }

    for (int l = 0; l < NL; l++) {
        if (!big) {
            transpose_bt<<<dim3(24, 24, 1), tb, 0, stream>>>(Wq, (size_t)l * WSQ, 0, wqkv,           0, ND, ND, flag);
            transpose_bt<<<dim3(24, 24, 1), tb, 0, stream>>>(Wk, (size_t)l * WSQ, 0, wqkv + WSQ,     0, ND, ND, flag);
            transpose_bt<<<dim3(24, 24, 1), tb, 0, stream>>>(Wv, (size_t)l * WSQ, 0, wqkv + 2 * WSQ, 0, ND, ND, flag);
            transpose_bt<<<dim3(24, 24, 1), tb, 0, stream>>>(Wo, (size_t)l * WSQ, 0, wo_t, 0, ND, ND, flag);
            transpose_bt<<<dim3(96, 24, 1), tb, 0, stream>>>(W1, (size_t)l * WF, 0, w1_t, 0, ND, NFF, flag);
            transpose_bt<<<dim3(24, 96, 1), tb, 0, stream>>>(W2, (size_t)l * WF, 0, w2_t, 0, NFF, ND, flag);
        }
        const bf16_t* wqkv_l = big ? wqkv + (size_t)l * WQKV_L : wqkv;
        const bf16_t* wo_l   = big ? wo_t + (size_t)l * WSQ : wo_t;
        const bf16_t* w1_l   = big ? w1_t + (size_t)l * WF : w1_t;
        const bf16_t* w2_l   = big ? w2_t + (size_t)l * WF : w2_t;

        gemm_bt<<<dim3(18, 64), 256, 0, stream>>>(xb, wqkv_l, bq, bk, bv, (size_t)l * ND, qkv, 2304, ND, 0, flag);
        attn<<<dim3(16, NH, NB), 256, 0, stream>>>(qkv, qkv + NQKV, qkv + 2 * NQKV, mask, ctxb);
        gemm_bt<<<dim3(6, 64), 256, 0, stream>>>(ctxb, wo_l, bo, nullptr, nullptr, (size_t)l * ND, x, ND, ND, 1, flag);
        ln_rows<<<NM, 256, 0, stream>>>(x, l1s, (size_t)l * ND, l1b, (size_t)l * ND, xb, flag);
        gemm_bt<<<dim3(24, 64), 256, 0, stream>>>(xb, w1_l, b1, nullptr, nullptr, (size_t)l * NFF, h1b, NFF, ND, 2, flag);
        gemm_bt<<<dim3(6, 64), 256, 0, stream>>>(h1b, w2_l, b2, nullptr, nullptr, (size_t)l * ND, x, ND, NFF, 1, flag);
        ln_rows<<<NM, 256, 0, stream>>>(x, l2s, (size_t)l * ND, l2b, (size_t)l * ND, xb, flag);
    }

    head_pre<<<dim3(3, NB), 256, 0, stream>>>(x, preW, preb, pr, flag);
    head_cls<<<NB, 256, 0, stream>>>(pr, clsW, clsb, d_out, flag);
}

// Round 6
// 2857.699 us; speedup vs baseline: 1.3106x; 1.2356x over previous
//
#include <hip/hip_runtime.h>

typedef __bf16 bf16_t;
typedef __bf16 bf16x8 __attribute__((ext_vector_type(8)));
typedef __bf16 bf16x4 __attribute__((ext_vector_type(4)));
typedef float f32x4 __attribute__((ext_vector_type(4)));

#define NB 16
#define NS 512
#define ND 768
#define NH 12
#define NFF 3072
#define NL 6
#define NHD 64
#define NM (NB*NS)   // 8192 token rows
static const size_t NQKV = (size_t)NB * NH * NS * NHD;   // 6,291,456 elems per Q/K/V buffer

static __device__ __forceinline__ f32x4 mfma16(bf16x8 a, bf16x8 b, f32x4 c) {
    return __builtin_amdgcn_mfma_f32_16x16x32_bf16(a, b, c, 0, 0, 0);
}

// dtype-dual load: isbf ? bf16[i] : f32[i]
static __device__ __forceinline__ float loadf(const void* p, size_t i, int isbf) {
    return isbf ? (float)((const bf16_t*)p)[i] : ((const float*)p)[i];
}

// async global->LDS, 16B per lane; LDS dest = wave-uniform base + lane*16
static __device__ __forceinline__ void gload_lds16(const bf16_t* g, bf16_t* l) {
    __builtin_amdgcn_global_load_lds((const __attribute__((address_space(1))) void*)g,
                                     (__attribute__((address_space(3))) void*)l, 16, 0, 0);
}

// -------------------- dtype detection (emb_ln_s is all-ones) --------------------
__global__ void detect_dtype(const void* elns, int* flag) {
    if (threadIdx.x == 0 && blockIdx.x == 0) {
        unsigned u = *(const unsigned*)elns;
        *flag = (u != 0x3F800000u) ? 1 : 0;
    }
}

// -------------------- weight transpose: src [K,N] (f32/bf16) -> dst bf16 [N,K] ------
__global__ __launch_bounds__(256) void transpose_bt(const void* __restrict__ src, size_t src_off,
                                                    size_t src_lstride,
                                                    bf16_t* __restrict__ dst, size_t dst_lstride,
                                                    int K, int N, const int* __restrict__ flagp) {
    const int isbf = flagp[0];
    __shared__ bf16_t t[32][33];
    int l = blockIdx.z;
    size_t so = src_off + (size_t)l * src_lstride;
    bf16_t* d = dst + (size_t)l * dst_lstride;
    int nn0 = blockIdx.x * 32, kk0 = blockIdx.y * 32;
    int tx = threadIdx.x, ty = threadIdx.y;  // 32 x 8
    #pragma unroll
    for (int i = 0; i < 4; i++)
        t[ty + i*8][tx] = (bf16_t)loadf(src, so + (size_t)(kk0 + ty + i*8) * N + nn0 + tx, isbf);
    __syncthreads();
    #pragma unroll
    for (int i = 0; i < 4; i++)
        d[(size_t)(nn0 + ty + i*8) * K + kk0 + tx] = t[tx][ty + i*8];
}

// -------------------- block reduce (sum,sumsq) over 256 threads --------------------
static __device__ __forceinline__ void blockReduce2(float& a, float& b, float* redbuf, int tid) {
    #pragma unroll
    for (int o = 32; o; o >>= 1) { a += __shfl_xor(a, o); b += __shfl_xor(b, o); }
    int wv = tid >> 6;
    if ((tid & 63) == 0) { redbuf[wv] = a; redbuf[4 + wv] = b; }
    __syncthreads();
    a = redbuf[0] + redbuf[1] + redbuf[2] + redbuf[3];
    b = redbuf[4] + redbuf[5] + redbuf[6] + redbuf[7];
    __syncthreads();
}

// -------------------- embedding segment-sum merge + pos emb + LN --------------------
__global__ __launch_bounds__(256) void embed_ln(const int* __restrict__ ids,
                                                const int* __restrict__ segs,
                                                const void* __restrict__ emb,
                                                const void* __restrict__ pos,
                                                const void* __restrict__ gamma,
                                                const void* __restrict__ beta,
                                                float* __restrict__ x, bf16_t* __restrict__ xb,
                                                const int* __restrict__ flagp) {
    const int isbf = flagp[0];
    int b = blockIdx.y, sq = blockIdx.x, tid = threadIdx.x;
    __shared__ int slo, shi;
    __shared__ float redbuf[8];
    if (tid == 0) { slo = 1 << 30; shi = -1; }
    __syncthreads();
    const int* segrow = segs + b * NS;
    const int* idrow  = ids  + b * NS;
    for (int p = tid; p < NS; p += 256)
        if (segrow[p] == sq) { atomicMin(&slo, p); atomicMax(&shi, p); }
    __syncthreads();
    int lo = slo, hi = shi;
    float vals[3];
    #pragma unroll
    for (int i = 0; i < 3; i++) {
        int d = tid + i * 256;
        float s;
        if (hi >= lo) {
            s = 0.f;
            for (int p = lo; p <= hi; p++) s += loadf(emb, (size_t)idrow[p] * ND + d, isbf);
        } else {
            s = loadf(emb, d, isbf);
        }
        vals[i] = s + loadf(pos, (size_t)sq * ND + d, isbf);
    }
    float sum = vals[0] + vals[1] + vals[2];
    float sq2 = vals[0]*vals[0] + vals[1]*vals[1] + vals[2]*vals[2];
    blockReduce2(sum, sq2, redbuf, tid);
    float mean = sum / ND;
    float var  = sq2 / ND - mean * mean;
    float rs = rsqrtf(fmaxf(var, 0.f) + 1e-12f);
    size_t rowoff = ((size_t)b * NS + sq) * ND;
    #pragma unroll
    for (int i = 0; i < 3; i++) {
        int d = tid + i * 256;
        float o = (vals[i] - mean) * rs * loadf(gamma, d, isbf) + loadf(beta, d, isbf);
        x[rowoff + d] = o;
        xb[rowoff + d] = (bf16_t)o;
    }
}

// -------------------- row LayerNorm in-place on f32 x, also emits bf16 xb ----------
__global__ __launch_bounds__(256) void ln_rows(float* __restrict__ x,
                                               const void* __restrict__ gamma, size_t goff,
                                               const void* __restrict__ beta, size_t boff,
                                               bf16_t* __restrict__ xb,
                                               const int* __restrict__ flagp) {
    const int isbf = flagp[0];
    int row = blockIdx.x, tid = threadIdx.x;
    __shared__ float redbuf[8];
    size_t rowoff = (size_t)row * ND;
    float vals[3];
    #pragma unroll
    for (int i = 0; i < 3; i++) vals[i] = x[rowoff + tid + i * 256];
    float sum = vals[0] + vals[1] + vals[2];
    float sq2 = vals[0]*vals[0] + vals[1]*vals[1] + vals[2]*vals[2];
    blockReduce2(sum, sq2, redbuf, tid);
    float mean = sum / ND;
    float var  = sq2 / ND - mean * mean;
    float rs = rsqrtf(fmaxf(var, 0.f) + 1e-12f);
    #pragma unroll
    for (int i = 0; i < 3; i++) {
        int d = tid + i * 256;
        float o = (vals[i] - mean) * rs * loadf(gamma, goff + d, isbf) + loadf(beta, boff + d, isbf);
        x[rowoff + d] = o;
        xb[rowoff + d] = (bf16_t)o;
    }
}

// -------------------- MFMA GEMM: C[M,N] = A[M,K] * Bt[N,K]^T + bias --------------------
// 128x128 tile, 4 waves, A+B staged in LDS double-buffer (2 x 32 KB = 64 KB,
// 2 blocks/CU). 16B-chunk XOR swizzle, global_load_lds dwordx4.
// T4 counted-vmcnt pipeline, 2 tiles in flight (NO vmcnt(0) drain in main loop):
//   compute(t from slot s) -> lgkmcnt(0)+barrier (slot s free) ->
//   stage(t+2 -> slot s)   -> vmcnt(8)+barrier (tile t+1 ready; t+2's 8 stay in flight)
// mode 0: fused QKV scatter -> q/k [B,H,S,HD] bf16, v TRANSPOSED [B,H,HD,S] bf16
//         (N_=2304, bias0/1/2)
// mode 1: f32 out[idx] += C + bias0      (in-place residual accumulate)
// mode 2: bf16 out = gelu(C + bias0)     (FF1)
__global__ __launch_bounds__(256) void gemm_bt(const bf16_t* __restrict__ A,
                                               const bf16_t* __restrict__ Bt,
                                               const void* __restrict__ bias0,
                                               const void* __restrict__ bias1,
                                               const void* __restrict__ bias2,
                                               size_t boff, void* __restrict__ out,
                                               int N_, int K_, int mode,
                                               const int* __restrict__ flagp) {
    const int isbf = flagp[0];
    __shared__ __align__(16) bf16_t As[2][128 * 64];
    __shared__ __align__(16) bf16_t Bs[2][128 * 64];
    int tid = threadIdx.x, wave = tid >> 6, lane = tid & 63;
    int lm = lane & 15, quad = lane >> 4;
    int m0 = blockIdx.y * 128, n0 = blockIdx.x * 128;
    int wm = (wave >> 1) * 64, wn = (wave & 1) * 64;
    f32x4 acc[4][4] = {};
    const bf16_t* Ag = A + (size_t)m0 * K_;
    const bf16_t* Bg = Bt + (size_t)n0 * K_;
    int lr = lane >> 3, lc = lane & 7;
    const int nt = K_ >> 6;

    auto stage = [&](int buf, int k0) {
        #pragma unroll
        for (int j = 0; j < 4; j++) {
            int sg = wave * 4 + j;            // 16 segments of 8 rows
            int r  = sg * 8 + lr;
            int c  = lc ^ (r & 7);            // fetch the chunk that belongs at slot lc
            gload_lds16(Ag + (size_t)r * K_ + k0 + c * 8, &As[buf][sg * 512]);
            gload_lds16(Bg + (size_t)r * K_ + k0 + c * 8, &Bs[buf][sg * 512]);
        }
    };

    // prologue: stage tiles 0 and 1; wait for tile 0 only (tile 1 stays in flight)
    stage(0, 0);
    if (nt > 1) {
        stage(1, 64);
        asm volatile("s_waitcnt vmcnt(8)" ::: "memory");
    } else {
        asm volatile("s_waitcnt vmcnt(0)" ::: "memory");
    }
    __builtin_amdgcn_s_barrier();

    for (int t = 0; t < nt; ++t) {
        int cur = t & 1;
        const bf16_t* Asb = &As[cur][0];
        const bf16_t* Bsb = &Bs[cur][0];
        __builtin_amdgcn_s_setprio(1);
        #pragma unroll
        for (int ks = 0; ks < 2; ks++) {
            bf16x8 af[4], bfv[4];
            #pragma unroll
            for (int tt = 0; tt < 4; tt++) {
                int ra = wm + tt*16 + lm;
                af[tt]  = *(const bf16x8*)(Asb + ra*64 + (((ks*4 + quad) ^ (ra & 7)) << 3));
                int rb = wn + tt*16 + lm;
                bfv[tt] = *(const bf16x8*)(Bsb + rb*64 + (((ks*4 + quad) ^ (rb & 7)) << 3));
            }
            #pragma unroll
            for (int mt = 0; mt < 4; mt++)
                #pragma unroll
                for (int ntt = 0; ntt < 4; ntt++)
                    acc[mt][ntt] = mfma16(af[mt], bfv[ntt], acc[mt][ntt]);
        }
        __builtin_amdgcn_s_setprio(0);
        if (t + 1 < nt) {
            // all my reads of slot cur are done -> slot reusable after barrier
            asm volatile("s_waitcnt lgkmcnt(0)" ::: "memory");
            __builtin_amdgcn_s_barrier();
            if (t + 2 < nt) {
                stage(cur, (t + 2) << 6);     // refill freed slot; 8 loads in flight
                asm volatile("s_waitcnt vmcnt(8)" ::: "memory");   // tile t+1 landed
            } else {
                asm volatile("s_waitcnt vmcnt(0)" ::: "memory");   // tail: drain
            }
            __builtin_amdgcn_s_barrier();     // everyone's tile t+1 loads landed
        }
    }

    if (mode == 0) {
        // fused QKV scatter; V goes out transposed [B,H,HD,S]
        #pragma unroll
        for (int mt = 0; mt < 4; mt++) {
            int mrow0 = m0 + wm + mt*16 + quad*4;      // 4 consecutive rows sp0..sp0+3
            int bbx = mrow0 >> 9, sp = mrow0 & 511;
            #pragma unroll
            for (int nt2 = 0; nt2 < 4; nt2++) {
                int ncol = n0 + wn + nt2*16 + lm;
                int which = ncol / 768;
                int col = ncol - which * 768;
                const void* bsel = which == 0 ? bias0 : (which == 1 ? bias1 : bias2);
                float bs = loadf(bsel, boff + col, isbf);
                int hh = col >> 6, hd = col & 63;
                if (which == 2) {
                    bf16x4 pk;
                    #pragma unroll
                    for (int r = 0; r < 4; r++) pk[r] = (bf16_t)(acc[mt][nt2][r] + bs);
                    bf16_t* vout = (bf16_t*)out + 2 * NQKV +
                                   (((size_t)(bbx*NH + hh)) * NHD + hd) * NS + sp;
                    *(bf16x4*)vout = pk;
                } else {
                    #pragma unroll
                    for (int r = 0; r < 4; r++)
                        ((bf16_t*)out)[(size_t)which * NQKV +
                                       (((size_t)(bbx*NH + hh) * NS) + sp + r) * NHD + hd] =
                            (bf16_t)(acc[mt][nt2][r] + bs);
                }
            }
        }
    } else {
        #pragma unroll
        for (int mt = 0; mt < 4; mt++)
        #pragma unroll
        for (int nt2 = 0; nt2 < 4; nt2++)
        #pragma unroll
        for (int r = 0; r < 4; r++) {
            int mrow = m0 + wm + mt*16 + quad*4 + r;
            int ncol = n0 + wn + nt2*16 + lm;
            float val = acc[mt][nt2][r] + loadf(bias0, boff + ncol, isbf);
            size_t idx = (size_t)mrow * N_ + ncol;
            if (mode == 1) {
                ((float*)out)[idx] += val;
            } else {
                float g = 0.5f * val * (1.0f + erff(val * 0.70710678118654752f));
                ((bf16_t*)out)[idx] = (bf16_t)g;
            }
        }
    }
}

// -------------------- fused attention: per (b,h,32 q rows) --------------
// K and V^T are L2-resident (64KB each per (b,h), reused by 16 q-blocks) ->
// load MFMA fragments DIRECT from global, no LDS staging, 3 barriers total.
__global__ __launch_bounds__(256) void attn(const bf16_t* __restrict__ q,
                                            const bf16_t* __restrict__ k,
                                            const bf16_t* __restrict__ vt,
                                            const int* __restrict__ mask,
                                            bf16_t* __restrict__ ctx) {
    __shared__ __align__(16) bf16_t sc[32][520];
    __shared__ float rinv[32];
    int tid = threadIdx.x, w = tid >> 6, lane = tid & 63;
    int lm = lane & 15, quad = lane >> 4;
    int mtw = w >> 1, nhw = w & 1;
    int b = blockIdx.z, h = blockIdx.y, q0 = blockIdx.x * 32;
    const bf16_t* Qg = q + (((size_t)(b*NH + h) * NS) + q0) * NHD;
    const bf16_t* Kg = k + ((size_t)(b*NH + h) * NS) * NHD;
    const bf16_t* Vt = vt + ((size_t)(b*NH + h) * NHD) * NS;   // [HD][S]
    bf16x8 aq0 = *(const bf16x8*)(Qg + (mtw*16 + lm) * NHD + quad*8);
    bf16x8 aq1 = *(const bf16x8*)(Qg + (mtw*16 + lm) * NHD + 32 + quad*8);
    // phase A: scores = Q K^T / 8 + mask bias (K fragments direct from L2)
    #pragma unroll 2
    for (int kc = 0; kc < NS; kc += 64) {
        #pragma unroll
        for (int nt = 0; nt < 2; nt++) {
            int ncl = nhw*32 + nt*16 + lm;
            int col = kc + ncl;
            bf16x8 b0 = *(const bf16x8*)(Kg + (size_t)col * NHD + quad*8);
            bf16x8 b1 = *(const bf16x8*)(Kg + (size_t)col * NHD + 32 + quad*8);
            f32x4 a = {};
            a = mfma16(aq0, b0, a);
            a = mfma16(aq1, b1, a);
            float mb = (mask[b*NS + col] == 0) ? -1e9f : 0.0f;
            #pragma unroll
            for (int r = 0; r < 4; r++)
                sc[mtw*16 + quad*4 + r][col] = (bf16_t)(a[r] * 0.125f + mb);
        }
    }
    __syncthreads();
    // phase B: softmax, all 32 rows in parallel (row = tid/8, 8 lanes per row)
    {
        int row = tid >> 3, part = tid & 7;
        bf16_t* base = &sc[row][part * 64];
        bf16x8 pv[8];
        float mx = -3.0e38f;
        #pragma unroll
        for (int i = 0; i < 8; i++) {
            pv[i] = *(const bf16x8*)(base + i * 8);
            #pragma unroll
            for (int j = 0; j < 8; j++) mx = fmaxf(mx, (float)pv[i][j]);
        }
        mx = fmaxf(mx, __shfl_xor(mx, 1));
        mx = fmaxf(mx, __shfl_xor(mx, 2));
        mx = fmaxf(mx, __shfl_xor(mx, 4));
        float sum = 0.f;
        #pragma unroll
        for (int i = 0; i < 8; i++) {
            bf16x8 pe;
            #pragma unroll
            for (int j = 0; j < 8; j++) {
                float p = __expf((float)pv[i][j] - mx);
                pe[j] = (bf16_t)p;
                sum += p;
            }
            *(bf16x8*)(base + i * 8) = pe;
        }
        sum += __shfl_xor(sum, 1);
        sum += __shfl_xor(sum, 2);
        sum += __shfl_xor(sum, 4);
        if (part == 0) rinv[row] = 1.0f / sum;
    }
    __syncthreads();
    // phase C: ctx = P V (V^T fragments direct from L2), scale by 1/sum at the end
    f32x4 oc[2] = {};
    #pragma unroll 2
    for (int kc = 0; kc < NS; kc += 64) {
        #pragma unroll
        for (int ks = 0; ks < 2; ks++) {
            bf16x8 ap = *(const bf16x8*)(&sc[mtw*16 + lm][kc + ks*32 + quad*8]);
            #pragma unroll
            for (int nt = 0; nt < 2; nt++) {
                int d = nhw*32 + nt*16 + lm;
                bf16x8 bv = *(const bf16x8*)(Vt + (size_t)d * NS + kc + ks*32 + quad*8);
                oc[nt] = mfma16(ap, bv, oc[nt]);
            }
        }
    }
    #pragma unroll
    for (int nt = 0; nt < 2; nt++)
    #pragma unroll
    for (int r = 0; r < 4; r++) {
        int row = mtw*16 + quad*4 + r;
        float val = oc[nt][r] * rinv[row];
        ctx[((size_t)(b*NS) + q0 + row) * ND + h*NHD + nhw*32 + nt*16 + lm] = (bf16_t)val;
    }
}

// -------------------- classifier head, stage 1: pr[b,n] = relu(x[b,0,:] @ preW + preb)
__global__ __launch_bounds__(256) void head_pre(const float* __restrict__ x,
                                                const void* __restrict__ preW,
                                                const void* __restrict__ preb,
                                                float* __restrict__ pr,
                                                const int* __restrict__ flagp) {
    const int isbf = flagp[0];
    int b = blockIdx.y;
    int n = blockIdx.x * 256 + threadIdx.x;
    const float* xr = x + (size_t)b * NS * ND;
    float s = loadf(preb, n, isbf);
    #pragma unroll 4
    for (int kk = 0; kk < ND; kk++) s += xr[kk] * loadf(preW, (size_t)kk * ND + n, isbf);
    pr[b * ND + n] = fmaxf(s, 0.f);
}

// -------------------- classifier head, stage 2: logits = pr @ clsW + clsb ----------
__global__ __launch_bounds__(256) void head_cls(const float* __restrict__ pr,
                                                const void* __restrict__ clsW,
                                                const void* __restrict__ clsb,
                                                void* __restrict__ out,
                                                const int* __restrict__ flagp) {
    const int isbf = flagp[0];
    int b = blockIdx.x, tid = threadIdx.x;
    __shared__ float red[256];
    for (int c = 0; c < 3; c++) {
        float s = 0.f;
        for (int kk = tid; kk < ND; kk += 256) s += pr[b * ND + kk] * loadf(clsW, kk * 3 + c, isbf);
        red[tid] = s;
        __syncthreads();
        for (int off = 128; off; off >>= 1) {
            if (tid < off) red[tid] += red[tid + off];
            __syncthreads();
        }
        if (tid == 0) {
            float v = red[0] + loadf(clsb, c, isbf);
            if (isbf) ((bf16_t*)out)[b * 3 + c] = (bf16_t)v;
            else      ((float*)out)[b * 3 + c] = v;
        }
        __syncthreads();
    }
}

extern "C" void kernel_launch(void* const* d_in, const int* in_sizes, int n_in,
                              void* d_out, int out_size, void* d_ws, size_t ws_size,
                              hipStream_t stream) {
    const int* ids   = (const int*)d_in[0];
    const int* segs  = (const int*)d_in[1];
    const int* mask  = (const int*)d_in[2];
    const void* emb  = d_in[4];
    const void* pos  = d_in[5];
    const void* elns = d_in[6];
    const void* elnb = d_in[7];
    const void* Wq = d_in[8];  const void* bq = d_in[9];
    const void* Wk = d_in[10]; const void* bk = d_in[11];
    const void* Wv = d_in[12]; const void* bv = d_in[13];
    const void* Wo = d_in[14]; const void* bo = d_in[15];
    const void* l1s = d_in[16]; const void* l1b = d_in[17];
    const void* W1 = d_in[18];  const void* b1 = d_in[19];
    const void* W2 = d_in[20];  const void* b2 = d_in[21];
    const void* l2s = d_in[22]; const void* l2b = d_in[23];
    const void* preW = d_in[24]; const void* preb = d_in[25];
    const void* clsW = d_in[26]; const void* clsb = d_in[27];

    // ---- workspace layout (deterministic function of ws_size) ----
    const size_t SZ_QKVB = NQKV * 2;                 // one of q/k/v/ctx, bf16
    size_t off = 0;
    auto alloc = [&](size_t sz) { size_t o = off; off = (off + sz + 255) & ~(size_t)255; return o; };
    size_t o_qkv  = alloc(3 * SZ_QKVB);              // q|k|v, also start of h1b alias
    size_t o_ctx  = alloc(SZ_QKVB);                  // h1b = [o_qkv .. o_ctx+SZ_QKVB) = 50.3MB
    size_t o_x    = alloc((size_t)NM * ND * 4);
    size_t o_xb   = alloc((size_t)NM * ND * 2);
    size_t o_pr   = alloc((size_t)NB * ND * 4);
    size_t o_flag = alloc(256);
    size_t o_w    = off;
    const size_t WQKV_L = (size_t)3 * ND * ND;       // per-layer fused qkv weight elems
    const size_t WSQ = (size_t)ND * ND, WF = (size_t)ND * NFF;
    size_t need_big = o_w + (NL * (WQKV_L + WSQ + 2 * WF)) * 2;
    int big = ws_size >= need_big;

    char* ws = (char*)d_ws;
    bf16_t* qkv  = (bf16_t*)(ws + o_qkv);
    bf16_t* ctxb = (bf16_t*)(ws + o_ctx);
    bf16_t* h1b  = (bf16_t*)(ws + o_qkv);
    float*  x    = (float*)(ws + o_x);
    bf16_t* xb   = (bf16_t*)(ws + o_xb);
    float*  pr   = (float*)(ws + o_pr);
    int*    flag = (int*)(ws + o_flag);
    size_t nlw = big ? NL : 1;
    bf16_t* wqkv = (bf16_t*)(ws + o_w);
    bf16_t* wo_t = wqkv + nlw * WQKV_L;
    bf16_t* w1_t = wo_t + nlw * WSQ;
    bf16_t* w2_t = w1_t + nlw * WF;

    detect_dtype<<<1, 64, 0, stream>>>(elns, flag);
    embed_ln<<<dim3(NS, NB), 256, 0, stream>>>(ids, segs, emb, pos, elns, elnb, x, xb, flag);

    dim3 tb(32, 8);
    if (big) {
        transpose_bt<<<dim3(24, 24, NL), tb, 0, stream>>>(Wq, 0, WSQ, wqkv,            WQKV_L, ND, ND, flag);
        transpose_bt<<<dim3(24, 24, NL), tb, 0, stream>>>(Wk, 0, WSQ, wqkv + WSQ,      WQKV_L, ND, ND, flag);
        transpose_bt<<<dim3(24, 24, NL), tb, 0, stream>>>(Wv, 0, WSQ, wqkv + 2 * WSQ,  WQKV_L, ND, ND, flag);
        transpose_bt<<<dim3(24, 24, NL), tb, 0, stream>>>(Wo, 0, WSQ, wo_t, WSQ, ND, ND, flag);
        transpose_bt<<<dim3(96, 24, NL), tb, 0, stream>>>(W1, 0, WF, w1_t, WF, ND, NFF, flag);
        transpose_bt<<<dim3(24, 96, NL), tb, 0, stream>>>(W2, 0, WF, w2_t, WF, NFF, ND, flag);
    }

    for (int l = 0; l < NL; l++) {
        if (!big) {
            transpose_bt<<<dim3(24, 24, 1), tb, 0, stream>>>(Wq, (size_t)l * WSQ, 0, wqkv,           0, ND, ND, flag);
            transpose_bt<<<dim3(24, 24, 1), tb, 0, stream>>>(Wk, (size_t)l * WSQ, 0, wqkv + WSQ,     0, ND, ND, flag);
            transpose_bt<<<dim3(24, 24, 1), tb, 0, stream>>>(Wv, (size_t)l * WSQ, 0, wqkv + 2 * WSQ, 0, ND, ND, flag);
            transpose_bt<<<dim3(24, 24, 1), tb, 0, stream>>>(Wo, (size_t)l * WSQ, 0, wo_t, 0, ND, ND, flag);
            transpose_bt<<<dim3(96, 24, 1), tb, 0, stream>>>(W1, (size_t)l * WF, 0, w1_t, 0, ND, NFF, flag);
            transpose_bt<<<dim3(24, 96, 1), tb, 0, stream>>>(W2, (size_t)l * WF, 0, w2_t, 0, NFF, ND, flag);
        }
        const bf16_t* wqkv_l = big ? wqkv + (size_t)l * WQKV_L : wqkv;
        const bf16_t* wo_l   = big ? wo_t + (size_t)l * WSQ : wo_t;
        const bf16_t* w1_l   = big ? w1_t + (size_t)l * WF : w1_t;
        const bf16_t* w2_l   = big ? w2_t + (size_t)l * WF : w2_t;

        gemm_bt<<<dim3(18, 64), 256, 0, stream>>>(xb, wqkv_l, bq, bk, bv, (size_t)l * ND, qkv, 2304, ND, 0, flag);
        attn<<<dim3(16, NH, NB), 256, 0, stream>>>(qkv, qkv + NQKV, qkv + 2 * NQKV, mask, ctxb);
        gemm_bt<<<dim3(6, 64), 256, 0, stream>>>(ctxb, wo_l, bo, nullptr, nullptr, (size_t)l * ND, x, ND, ND, 1, flag);
        ln_rows<<<NM, 256, 0, stream>>>(x, l1s, (size_t)l * ND, l1b, (size_t)l * ND, xb, flag);
        gemm_bt<<<dim3(24, 64), 256, 0, stream>>>(xb, w1_l, b1, nullptr, nullptr, (size_t)l * NFF, h1b, NFF, ND, 2, flag);
        gemm_bt<<<dim3(6, 64), 256, 0, stream>>>(h1b, w2_l, b2, nullptr, nullptr, (size_t)l * ND, x, ND, NFF, 1, flag);
        ln_rows<<<NM, 256, 0, stream>>>(x, l2s, (size_t)l * ND, l2b, (size_t)l * ND, xb, flag);
    }

    head_pre<<<dim3(3, NB), 256, 0, stream>>>(x, preW, preb, pr, flag);
    head_cls<<<NB, 256, 0, stream>>>(pr, clsW, clsb, d_out, flag);
}